// Round 9
// baseline (657.499 us; speedup 1.0000x reference)
//
#include <hip/hip_runtime.h>

typedef __bf16 bf16_t;
typedef __bf16 bf16x8 __attribute__((ext_vector_type(8)));
typedef __bf16 bf16x4 __attribute__((ext_vector_type(4)));
typedef float  f32x4  __attribute__((ext_vector_type(4)));
typedef int    i32x4  __attribute__((ext_vector_type(4)));

#define PL 136   // padded row stride (elems) for [t][128] bf16 tiles
#define PX 264   // padded row stride (elems) for [t][256] bf16 tiles

__device__ __forceinline__ f32x4 mfma16(bf16x8 a, bf16x8 b, f32x4 c) {
    return __builtin_amdgcn_mfma_f32_16x16x32_bf16(a, b, c, 0, 0, 0);
}

// ---------------- merged weight conversion ----------------
__device__ __forceinline__ void conv_elem(const float* __restrict__ src,
                                          bf16_t* __restrict__ dst,
                                          int idx, int M, int K) {
    int MK = M * K;
    int lay = idx / MK;
    int r = idx - lay * MK;
    int j = r & 7, lane = (r >> 3) & 63, rest = r >> 9;
    int KB = K >> 5;
    int kb = rest % KB, mt = rest / KB;
    int m = mt * 16 + (lane & 15);
    int k = kb * 32 + ((lane >> 4) << 3) + j;
    dst[idx] = (bf16_t)src[(size_t)lay * MK + m * K + k];
}

__global__ void conv_all(const float* __restrict__ rw, const float* __restrict__ kw,
                         const float* __restrict__ s1w, const float* __restrict__ s2w,
                         const float* __restrict__ e1w, const float* __restrict__ dwt,
                         bf16_t* __restrict__ Ares, bf16_t* __restrict__ Askp,
                         bf16_t* __restrict__ A1, bf16_t* __restrict__ A2,
                         bf16_t* __restrict__ Ae, bf16_t* __restrict__ Adil) {
    int idx = blockIdx.x * 256 + threadIdx.x;
    if (idx < 491520) { conv_elem(rw, Ares, idx, 128, 128); return; }
    idx -= 491520;
    if (idx < 983040) { conv_elem(kw, Askp, idx, 256, 128); return; }
    idx -= 983040;
    if (idx < 32768) { conv_elem(s1w, A1, idx, 128, 256); return; }
    idx -= 32768;
    if (idx < 32768) { conv_elem(s2w, A2, idx, 256, 128); return; }
    idx -= 32768;
    if (idx < 65536) { conv_elem(e1w, Ae, idx, 256, 256); return; }
    idx -= 65536;
    if (idx < 1966080) {   // dil_w -> per-layer A[256][256]
        int lay = idx >> 16, r = idx & 65535;
        int j = r & 7, lane = (r >> 3) & 63, rest = r >> 9;
        int kb = rest & 7, mt = rest >> 3;
        int m = mt * 16 + (lane & 15);
        int k = kb * 32 + ((lane >> 4) << 3) + j;
        float v = (k < 128) ? dwt[(((size_t)lay * 256 + m) * 128 + k) * 2]
                            : dwt[(((size_t)lay * 256 + m) * 128 + (k - 128)) * 2 + 1];
        Adil[(size_t)lay * 65536 + r] = (bf16_t)v;
    }
}

// ---------------- conditioning precompute ----------------
__global__ void cond_kernel(const float* __restrict__ cond_w,
                            const float* __restrict__ end2_w,
                            const float* __restrict__ end2_b,
                            const float* __restrict__ en,
                            float* __restrict__ cond_all,
                            float* __restrict__ cond2) {
    __shared__ f32x4 en_s[1024];
    int bi = blockIdx.x;
    int i = bi >> 2, n = bi & 3, o = threadIdx.x;
    const f32x4* ep = (const f32x4*)(en + (size_t)n * 4096);
    for (int idx = threadIdx.x; idx < 1024; idx += 256) en_s[idx] = ep[idx];
    __syncthreads();
    const float* W = (i < 30) ? cond_w + ((size_t)i * 256 + o) * 256
                              : end2_w + (size_t)o * 256;
    f32x4 a0 = {0.f,0.f,0.f,0.f}, a1 = a0, a2 = a0, a3 = a0;
    for (int c = 0; c < 256; c += 4) {
        f32x4 wv = *(const f32x4*)(W + c);
        #pragma unroll
        for (int cc = 0; cc < 4; ++cc) {
            float wf = wv[cc];
            a0 += wf * en_s[(c + cc) * 4 + 0];
            a1 += wf * en_s[(c + cc) * 4 + 1];
            a2 += wf * en_s[(c + cc) * 4 + 2];
            a3 += wf * en_s[(c + cc) * 4 + 3];
        }
    }
    float bias = (i < 30) ? 0.f : end2_b[o];
    float* dst = (i < 30) ? cond_all + (((size_t)i * 4 + n) * 256 + o) * 16
                          : cond2 + ((size_t)n * 256 + o) * 16;
    f32x4* d4 = (f32x4*)dst;
    d4[0] = a0 + bias; d4[1] = a1 + bias; d4[2] = a2 + bias; d4[3] = a3 + bias;
}

// ---------------- start: l0 = start1@x ; s0 = start2@l0 (t>=4096) ----------------
__global__ __launch_bounds__(512, 4) void k_start(
    const float* __restrict__ x, bf16_t* __restrict__ la, float* __restrict__ sbuf,
    const bf16_t* __restrict__ A1, const bf16_t* __restrict__ A2, int t_base)
{
    __shared__ __align__(16) bf16_t xt[64 * PX];
    __shared__ __align__(16) bf16_t l0[64 * PL];
    int tid = threadIdx.x;
    int n = blockIdx.y, t0 = t_base + blockIdx.x * 64;
    int lane = tid & 63, w = tid >> 6, i16 = lane & 15, q = lane >> 4;
    f32x4 z = {0.f,0.f,0.f,0.f};
    {
        int t = tid & 63;
        for (int c = tid >> 6; c < 256; c += 8)
            xt[t * PX + c] = (bf16_t)x[((size_t)n * 256 + c) * 8192 + t0 + t];
    }
    __syncthreads();
    f32x4 acc[4] = {z,z,z,z};
    #pragma unroll
    for (int kb = 0; kb < 8; ++kb) {
        int koff = kb * 32 + q * 8;
        bf16x8 bf[4];
        #pragma unroll
        for (int nt = 0; nt < 4; ++nt)
            bf[nt] = *(const bf16x8*)(xt + (nt * 16 + i16) * PX + koff);
        bf16x8 af = *(const bf16x8*)(A1 + (((size_t)w * 8 + kb) * 64 + lane) * 8);
        #pragma unroll
        for (int nt = 0; nt < 4; ++nt) acc[nt] = mfma16(af, bf[nt], acc[nt]);
    }
    #pragma unroll
    for (int nt = 0; nt < 4; ++nt)
        #pragma unroll
        for (int j = 0; j < 4; ++j)
            l0[(nt * 16 + i16) * PL + w * 16 + q * 4 + j] = (bf16_t)acc[nt][j];
    __syncthreads();
    {
        int r = tid >> 4, col = (tid & 15) * 8;
        #pragma unroll
        for (int p = 0; p < 2; ++p) {
            int rr = r + p * 32;
            *(i32x4*)(la + ((size_t)n * 8192 + t0 + rr) * 128 + col) =
                *(const i32x4*)(l0 + rr * PL + col);
        }
    }
    if (t0 >= 4096) {
        f32x4 a2[2][4] = {{z,z,z,z},{z,z,z,z}};
        #pragma unroll
        for (int kb = 0; kb < 4; ++kb) {
            int koff = kb * 32 + q * 8;
            bf16x8 bf[4];
            #pragma unroll
            for (int nt = 0; nt < 4; ++nt)
                bf[nt] = *(const bf16x8*)(l0 + (nt * 16 + i16) * PL + koff);
            #pragma unroll
            for (int mt2 = 0; mt2 < 2; ++mt2) {
                bf16x8 af = *(const bf16x8*)(A2 + ((((size_t)2 * w + mt2) * 4 + kb) * 64 + lane) * 8);
                #pragma unroll
                for (int nt = 0; nt < 4; ++nt) a2[mt2][nt] = mfma16(af, bf[nt], a2[mt2][nt]);
            }
        }
        float* sp = sbuf + (size_t)n * 256 * 4096 + (t0 - 4096);
        #pragma unroll
        for (int mt2 = 0; mt2 < 2; ++mt2)
            #pragma unroll
            for (int nt = 0; nt < 4; ++nt)
                #pragma unroll
                for (int j = 0; j < 4; ++j) {
                    int o = (2 * w + mt2) * 16 + q * 4 + j;
                    sp[(size_t)o * 4096 + nt * 16 + i16] = a2[mt2][nt][j];
                }
    }
}

// ---------------- single layer, TT=32 rows/block, full occupancy ----------------
// USEG=1: stream bf16 gate tile to Gl; skip GEMM deferred to k_skip.
// USEG=0: legacy in-layer skip GEMM + sbuf RMW (ws-size fallback).
template<int USEG>
__global__ __launch_bounds__(512, 8) void k_layer(
    const bf16_t* __restrict__ l_in, bf16_t* __restrict__ l_out,
    float* __restrict__ sbuf, bf16_t* __restrict__ Gl,
    const bf16_t* __restrict__ Ad, const bf16_t* __restrict__ Ar,
    const bf16_t* __restrict__ Ak, const float* __restrict__ condL,
    int dil, int t_base, int do_res)
{
    __shared__ __align__(16) bf16_t sm0[32 * PL];   // l_cur
    __shared__ __align__(16) bf16_t sm1[32 * PL];   // l_del -> bf16 res sum
    __shared__ __align__(16) bf16_t sm2[32 * PL];   // gate
    int tid = threadIdx.x;
    int n = blockIdx.y, t0 = t_base + blockIdx.x * 32;
    int lane = tid & 63, w = tid >> 6, i16 = lane & 15, q = lane >> 4;
    f32x4 z = {0.f,0.f,0.f,0.f};
    const float* cond = condL + (size_t)n * 4096;
    int r = tid >> 4, col = (tid & 15) * 8;
    {
        size_t base = (size_t)n * 8192;
        *(i32x4*)(sm0 + r * PL + col) =
            *(const i32x4*)(l_in + (base + t0 + r) * 128 + col);
        int gp = t0 - dil + r;
        i32x4 v = {0, 0, 0, 0};
        if (gp >= 0) v = *(const i32x4*)(l_in + (base + gp) * 128 + col);
        *(i32x4*)(sm1 + r * PL + col) = v;
    }
    __syncthreads();

    // GEMM1: d = [W0 W1] @ [l_del; l_cur], M=256 K=256, N=32
    f32x4 accs[2] = {z,z}, acct[2] = {z,z};
    const bf16x8* AdF = (const bf16x8*)Ad;
    #pragma unroll
    for (int kb = 0; kb < 8; ++kb) {
        const bf16_t* bsrc = (kb < 4) ? sm1 : sm0;
        int koff = (kb & 3) * 32 + q * 8;
        bf16x8 bf[2];
        #pragma unroll
        for (int nt = 0; nt < 2; ++nt)
            bf[nt] = *(const bf16x8*)(bsrc + (nt * 16 + i16) * PL + koff);
        bf16x8 a_s = AdF[((size_t)w * 8 + kb) * 64 + lane];
        bf16x8 a_t = AdF[((size_t)(w + 8) * 8 + kb) * 64 + lane];
        #pragma unroll
        for (int nt = 0; nt < 2; ++nt) {
            accs[nt] = mfma16(a_s, bf[nt], accs[nt]);
            acct[nt] = mfma16(a_t, bf[nt], acct[nt]);
        }
    }
    int c_base = w * 16 + q * 4;
    {   // gate in-register -> sm2
        float cv_s[4], cv_t[4];
        #pragma unroll
        for (int j = 0; j < 4; ++j) {
            cv_s[j] = cond[(c_base + j) * 16 + i16];
            cv_t[j] = cond[(c_base + j + 128) * 16 + i16];
        }
        #pragma unroll
        for (int nt = 0; nt < 2; ++nt) {
            bf16x4 g4;
            #pragma unroll
            for (int j = 0; j < 4; ++j) {
                float vlo = accs[nt][j] + cv_s[j];
                float vhi = acct[nt][j] + cv_t[j];
                float sg = 1.0f / (1.0f + __expf(-vlo));
                float th = 1.0f - 2.0f / (1.0f + __expf(2.0f * vhi));
                g4[j] = (bf16_t)(sg * th);
            }
            *(bf16x4*)(sm2 + (nt * 16 + i16) * PL + c_base) = g4;
        }
    }
    __syncthreads();

    if (USEG) {
        if (t0 >= 4096) {   // stream gate tile to G
            bf16_t* gd = Gl + ((size_t)n * 4096 + (t0 - 4096) + r) * 128 + col;
            *(i32x4*)gd = *(const i32x4*)(sm2 + r * PL + col);
        }
    }

    f32x4 acc2[2] = {z,z};
    const bf16x8* ArF = (const bf16x8*)Ar;
    if (do_res || !USEG) {
        int do_skip = (!USEG) && (t0 >= 4096);
        f32x4 acc3[2][2] = {{z,z},{z,z}};
        const bf16x8* AkF = (const bf16x8*)Ak;
        #pragma unroll
        for (int kb = 0; kb < 4; ++kb) {
            int koff = kb * 32 + q * 8;
            bf16x8 bf[2];
            #pragma unroll
            for (int nt = 0; nt < 2; ++nt)
                bf[nt] = *(const bf16x8*)(sm2 + (nt * 16 + i16) * PL + koff);
            if (do_res) {
                bf16x8 ar = ArF[((size_t)w * 4 + kb) * 64 + lane];
                #pragma unroll
                for (int nt = 0; nt < 2; ++nt) acc2[nt] = mfma16(ar, bf[nt], acc2[nt]);
            }
            if (do_skip) {
                #pragma unroll
                for (int mt2 = 0; mt2 < 2; ++mt2) {
                    bf16x8 ak = AkF[((size_t)(2 * w + mt2) * 4 + kb) * 64 + lane];
                    #pragma unroll
                    for (int nt = 0; nt < 2; ++nt)
                        acc3[mt2][nt] = mfma16(ak, bf[nt], acc3[mt2][nt]);
                }
            }
        }
        if (do_skip) {
            float* sp = sbuf + (size_t)n * 256 * 4096 + (t0 - 4096);
            #pragma unroll
            for (int mt2 = 0; mt2 < 2; ++mt2)
                #pragma unroll
                for (int nt = 0; nt < 2; ++nt)
                    #pragma unroll
                    for (int j = 0; j < 4; ++j) {
                        int o = (2 * w + mt2) * 16 + q * 4 + j;
                        sp[(size_t)o * 4096 + nt * 16 + i16] += acc3[mt2][nt][j];
                    }
        }
    }

    if (do_res) {
        #pragma unroll
        for (int nt = 0; nt < 2; ++nt) {
            int trow = (nt * 16 + i16) * PL;
            bf16x4 lv = *(const bf16x4*)(sm0 + trow + c_base);
            bf16x4 o4;
            #pragma unroll
            for (int j = 0; j < 4; ++j)
                o4[j] = (bf16_t)((float)lv[j] + acc2[nt][j]);
            *(bf16x4*)(sm1 + trow + c_base) = o4;
        }
        __syncthreads();
        bf16_t* dst = l_out + ((size_t)n * 8192 + t0 + r) * 128 + col;
        *(i32x4*)dst = *(const i32x4*)(sm1 + r * PL + col);
    }
}

// ---------------- deferred skip mega-GEMM: s += sum_i skip_i @ g_i ----------------
// TT=32, depth-2 register prefetch ring over the 30-layer K-chain.
__global__ __launch_bounds__(512, 8) void k_skip(
    const bf16_t* __restrict__ G, float* __restrict__ sbuf,
    const bf16_t* __restrict__ Askp)
{
    __shared__ __align__(16) bf16_t gbuf[32 * PL];
    int tid = threadIdx.x;
    int n = blockIdx.y, t0 = blockIdx.x * 32;
    int lane = tid & 63, w = tid >> 6, i16 = lane & 15, q = lane >> 4;
    f32x4 z = {0.f,0.f,0.f,0.f};
    f32x4 acc[2][2] = {{z,z},{z,z}};
    int r = tid >> 4, cA = (tid & 15) * 8;
    const size_t GLS = (size_t)4 * 4096 * 128;   // per-layer stride in G
    const bf16_t* gb = G + ((size_t)n * 4096 + t0 + r) * 128 + cA;
    i32x4 v[2];
    v[0] = *(const i32x4*)(gb);
    v[1] = *(const i32x4*)(gb + GLS);
    #pragma unroll 1
    for (int i = 0; i < 30; ++i) {
        __syncthreads();
        *(i32x4*)(gbuf + r * PL + cA) = v[i & 1];
        if (i + 2 < 30) v[i & 1] = *(const i32x4*)(gb + (size_t)(i + 2) * GLS);
        __syncthreads();
        const bf16x8* AkF = (const bf16x8*)(Askp + (size_t)i * 32768);
        #pragma unroll
        for (int kb = 0; kb < 4; ++kb) {
            int koff = kb * 32 + q * 8;
            bf16x8 ak0 = AkF[((size_t)(2 * w) * 4 + kb) * 64 + lane];
            bf16x8 ak1 = AkF[((size_t)(2 * w + 1) * 4 + kb) * 64 + lane];
            #pragma unroll
            for (int nt = 0; nt < 2; ++nt) {
                bf16x8 bf = *(const bf16x8*)(gbuf + (nt * 16 + i16) * PL + koff);
                acc[0][nt] = mfma16(ak0, bf, acc[0][nt]);
                acc[1][nt] = mfma16(ak1, bf, acc[1][nt]);
            }
        }
    }
    float* sp = sbuf + (size_t)n * 256 * 4096 + t0;
    #pragma unroll
    for (int mt2 = 0; mt2 < 2; ++mt2)
        #pragma unroll
        for (int nt = 0; nt < 2; ++nt)
            #pragma unroll
            for (int j = 0; j < 4; ++j) {
                int o = (2 * w + mt2) * 16 + q * 4 + j;
                sp[(size_t)o * 4096 + nt * 16 + i16] += acc[mt2][nt][j];
            }
}

// ---------------- end: out = relu(end1@relu(s) + b1 + cond2_tiled) ----------------
__global__ __launch_bounds__(512) void k_end(
    const float* __restrict__ sbuf, float* __restrict__ out,
    const bf16_t* __restrict__ Ae, const float* __restrict__ cond2,
    const float* __restrict__ b1)
{
    __shared__ __align__(16) bf16_t st[64 * PX];
    __shared__ float c2[4096];
    __shared__ float b1s[256];
    int tid = threadIdx.x;
    int n = blockIdx.y, t0 = blockIdx.x * 64;
    int lane = tid & 63, w = tid >> 6, i16 = lane & 15, q = lane >> 4;
    f32x4 z = {0.f,0.f,0.f,0.f};
    {
        int t = tid & 63;
        for (int c = tid >> 6; c < 256; c += 8) {
            float v = sbuf[((size_t)n * 256 + c) * 4096 + t0 + t];
            st[t * PX + c] = (bf16_t)fmaxf(v, 0.f);
        }
        const f32x4* cc = (const f32x4*)(cond2 + (size_t)n * 4096);
        for (int idx = tid; idx < 1024; idx += 512) ((f32x4*)c2)[idx] = cc[idx];
        if (tid < 64) ((f32x4*)b1s)[tid] = ((const f32x4*)b1)[tid];
    }
    __syncthreads();
    f32x4 acc[2][4] = {{z,z,z,z},{z,z,z,z}};
    #pragma unroll
    for (int kb = 0; kb < 8; ++kb) {
        int koff = kb * 32 + q * 8;
        bf16x8 bf[4];
        #pragma unroll
        for (int nt = 0; nt < 4; ++nt)
            bf[nt] = *(const bf16x8*)(st + (nt * 16 + i16) * PX + koff);
        #pragma unroll
        for (int mt2 = 0; mt2 < 2; ++mt2) {
            bf16x8 af = *(const bf16x8*)(Ae + ((((size_t)2 * w + mt2) * 8 + kb) * 64 + lane) * 8);
            #pragma unroll
            for (int nt = 0; nt < 4; ++nt) acc[mt2][nt] = mfma16(af, bf[nt], acc[mt2][nt]);
        }
    }
    #pragma unroll
    for (int mt2 = 0; mt2 < 2; ++mt2)
        #pragma unroll
        for (int j = 0; j < 4; ++j) {
            int o = (2 * w + mt2) * 16 + q * 4 + j;
            float bb = b1s[o] + c2[o * 16 + i16];
            #pragma unroll
            for (int nt = 0; nt < 4; ++nt) {
                float v = acc[mt2][nt][j] + bb;
                out[((size_t)n * 256 + o) * 4096 + t0 + nt * 16 + i16] = fmaxf(v, 0.f);
            }
        }
}

extern "C" void kernel_launch(void* const* d_in, const int* in_sizes, int n_in,
                              void* d_out, int out_size, void* d_ws, size_t ws_size,
                              hipStream_t stream) {
    const float* x   = (const float*)d_in[0];
    const float* en  = (const float*)d_in[1];
    const float* s1w = (const float*)d_in[2];
    const float* s2w = (const float*)d_in[3];
    const float* cw  = (const float*)d_in[4];
    const float* dw  = (const float*)d_in[5];
    const float* rw  = (const float*)d_in[6];
    const float* kw  = (const float*)d_in[7];
    const float* e1w = (const float*)d_in[8];
    const float* e1b = (const float*)d_in[9];
    const float* e2w = (const float*)d_in[10];
    const float* e2b = (const float*)d_in[11];
    float* out = (float*)d_out;

    char* p = (char*)d_ws;
    auto take = [&](size_t bytes) {
        char* r = p;
        p += (bytes + 255) & ~(size_t)255;
        return r;
    };
    bf16_t* A1   = (bf16_t*)take((size_t)128 * 256 * 2);
    bf16_t* A2   = (bf16_t*)take((size_t)256 * 128 * 2);
    bf16_t* Ae   = (bf16_t*)take((size_t)256 * 256 * 2);
    bf16_t* Adil = (bf16_t*)take((size_t)30 * 65536 * 2);
    bf16_t* Ares = (bf16_t*)take((size_t)30 * 16384 * 2);
    bf16_t* Askp = (bf16_t*)take((size_t)30 * 32768 * 2);
    float*  condA= (float*)take((size_t)30 * 16384 * 4);
    float*  cond2= (float*)take((size_t)16384 * 4);
    bf16_t* la   = (bf16_t*)take((size_t)4 * 8192 * 128 * 2);
    bf16_t* lb   = (bf16_t*)take((size_t)4 * 8192 * 128 * 2);
    float*  sbuf = (float*)take((size_t)4 * 256 * 4096 * 4);
    bf16_t* G    = (bf16_t*)take((size_t)30 * 4 * 4096 * 128 * 2);  // last
    bool useG = ((size_t)(p - (char*)d_ws) <= ws_size);

    conv_all<<<13952, 256, 0, stream>>>(rw, kw, s1w, s2w, e1w, dw,
                                        Ares, Askp, A1, A2, Ae, Adil);
    cond_kernel<<<124, 256, 0, stream>>>(cw, e2w, e2b, en, condA, cond2);

    // causal trim table (host)
    int a[30];
    a[29] = 4096;
    for (int i = 28; i >= 0; --i) {
        int nx = a[i + 1] - (1 << ((i + 1) % 10));
        a[i] = nx < 4096 ? (nx & ~63) : 4096;
    }

    k_start<<<dim3(127, 4), 512, 0, stream>>>(x, la, sbuf, A1, A2, 64);

    bf16_t* src = la;
    bf16_t* dst = lb;
    for (int i = 0; i < 30; ++i) {
        dim3 grid((8192 - a[i]) / 32, 4);
        if (useG)
            k_layer<1><<<grid, 512, 0, stream>>>(src, dst, sbuf,
                G + (size_t)i * 4 * 4096 * 128,
                Adil + (size_t)i * 65536, Ares + (size_t)i * 16384,
                Askp + (size_t)i * 32768, condA + (size_t)i * 16384,
                1 << (i % 10), a[i], i < 29 ? 1 : 0);
        else
            k_layer<0><<<grid, 512, 0, stream>>>(src, dst, sbuf, (bf16_t*)nullptr,
                Adil + (size_t)i * 65536, Ares + (size_t)i * 16384,
                Askp + (size_t)i * 32768, condA + (size_t)i * 16384,
                1 << (i % 10), a[i], i < 29 ? 1 : 0);
        bf16_t* t = src; src = dst; dst = t;
    }
    if (useG)
        k_skip<<<dim3(128, 4), 512, 0, stream>>>(G, sbuf, Askp);
    k_end<<<dim3(64, 4), 512, 0, stream>>>(sbuf, out, Ae, cond2, e1b);
}

// Round 10
// 633.161 us; speedup vs baseline: 1.0384x; 1.0384x over previous
//
#include <hip/hip_runtime.h>

typedef __bf16 bf16_t;
typedef __bf16 bf16x8 __attribute__((ext_vector_type(8)));
typedef __bf16 bf16x4 __attribute__((ext_vector_type(4)));
typedef float  f32x4  __attribute__((ext_vector_type(4)));
typedef int    i32x4  __attribute__((ext_vector_type(4)));

#define PL 136   // padded row stride (elems) for [t][128] bf16 tiles
#define PX 264   // padded row stride (elems) for [t][256] bf16 tiles

__device__ __forceinline__ f32x4 mfma16(bf16x8 a, bf16x8 b, f32x4 c) {
    return __builtin_amdgcn_mfma_f32_16x16x32_bf16(a, b, c, 0, 0, 0);
}

// ---------------- merged prep: weight conversion + conditioning ----------------
__device__ __forceinline__ void conv_elem(const float* __restrict__ src,
                                          bf16_t* __restrict__ dst,
                                          int idx, int M, int K) {
    int MK = M * K;
    int lay = idx / MK;
    int r = idx - lay * MK;
    int j = r & 7, lane = (r >> 3) & 63, rest = r >> 9;
    int KB = K >> 5;
    int kb = rest % KB, mt = rest / KB;
    int m = mt * 16 + (lane & 15);
    int k = kb * 32 + ((lane >> 4) << 3) + j;
    dst[idx] = (bf16_t)src[(size_t)lay * MK + m * K + k];
}

__global__ void k_prep(const float* __restrict__ rw, const float* __restrict__ kw,
                       const float* __restrict__ s1w, const float* __restrict__ s2w,
                       const float* __restrict__ e1w, const float* __restrict__ dwt,
                       const float* __restrict__ cond_w, const float* __restrict__ end2_w,
                       const float* __restrict__ end2_b, const float* __restrict__ en,
                       bf16_t* __restrict__ Ares, bf16_t* __restrict__ Askp,
                       bf16_t* __restrict__ A1, bf16_t* __restrict__ A2,
                       bf16_t* __restrict__ Ae, bf16_t* __restrict__ Adil,
                       float* __restrict__ cond_all, float* __restrict__ cond2) {
    __shared__ f32x4 en_s[1024];
    if (blockIdx.x >= 13952) {
        // conditioning: bi in [0,124)
        int bi = blockIdx.x - 13952;
        int i = bi >> 2, n = bi & 3, o = threadIdx.x;
        const f32x4* ep = (const f32x4*)(en + (size_t)n * 4096);
        for (int idx = threadIdx.x; idx < 1024; idx += 256) en_s[idx] = ep[idx];
        __syncthreads();
        const float* W = (i < 30) ? cond_w + ((size_t)i * 256 + o) * 256
                                  : end2_w + (size_t)o * 256;
        f32x4 a0 = {0.f,0.f,0.f,0.f}, a1 = a0, a2 = a0, a3 = a0;
        for (int c = 0; c < 256; c += 4) {
            f32x4 wv = *(const f32x4*)(W + c);
            #pragma unroll
            for (int cc = 0; cc < 4; ++cc) {
                float wf = wv[cc];
                a0 += wf * en_s[(c + cc) * 4 + 0];
                a1 += wf * en_s[(c + cc) * 4 + 1];
                a2 += wf * en_s[(c + cc) * 4 + 2];
                a3 += wf * en_s[(c + cc) * 4 + 3];
            }
        }
        float bias = (i < 30) ? 0.f : end2_b[o];
        float* dst = (i < 30) ? cond_all + (((size_t)i * 4 + n) * 256 + o) * 16
                              : cond2 + ((size_t)n * 256 + o) * 16;
        f32x4* d4 = (f32x4*)dst;
        d4[0] = a0 + bias; d4[1] = a1 + bias; d4[2] = a2 + bias; d4[3] = a3 + bias;
        return;
    }
    int idx = blockIdx.x * 256 + threadIdx.x;
    if (idx < 491520) { conv_elem(rw, Ares, idx, 128, 128); return; }
    idx -= 491520;
    if (idx < 983040) { conv_elem(kw, Askp, idx, 256, 128); return; }
    idx -= 983040;
    if (idx < 32768) { conv_elem(s1w, A1, idx, 128, 256); return; }
    idx -= 32768;
    if (idx < 32768) { conv_elem(s2w, A2, idx, 256, 128); return; }
    idx -= 32768;
    if (idx < 65536) { conv_elem(e1w, Ae, idx, 256, 256); return; }
    idx -= 65536;
    {   // dil_w -> per-layer A[256][256]
        int lay = idx >> 16, r = idx & 65535;
        int j = r & 7, lane = (r >> 3) & 63, rest = r >> 9;
        int kb = rest & 7, mt = rest >> 3;
        int m = mt * 16 + (lane & 15);
        int k = kb * 32 + ((lane >> 4) << 3) + j;
        float v = (k < 128) ? dwt[(((size_t)lay * 256 + m) * 128 + k) * 2]
                            : dwt[(((size_t)lay * 256 + m) * 128 + (k - 128)) * 2 + 1];
        Adil[(size_t)lay * 65536 + r] = (bf16_t)v;
    }
}

// ---------------- start: l0 = start1@x ; s0 = start2@l0 (t>=4096) ----------------
__global__ __launch_bounds__(512, 4) void k_start(
    const float* __restrict__ x, bf16_t* __restrict__ la, float* __restrict__ sbuf,
    const bf16_t* __restrict__ A1, const bf16_t* __restrict__ A2, int t_base)
{
    __shared__ __align__(16) bf16_t xt[64 * PX];
    __shared__ __align__(16) bf16_t l0[64 * PL];
    int tid = threadIdx.x;
    int n = blockIdx.y, t0 = t_base + blockIdx.x * 64;
    int lane = tid & 63, w = tid >> 6, i16 = lane & 15, q = lane >> 4;
    f32x4 z = {0.f,0.f,0.f,0.f};
    {
        int t = tid & 63;
        for (int c = tid >> 6; c < 256; c += 8)
            xt[t * PX + c] = (bf16_t)x[((size_t)n * 256 + c) * 8192 + t0 + t];
    }
    __syncthreads();
    f32x4 acc[4] = {z,z,z,z};
    #pragma unroll
    for (int kb = 0; kb < 8; ++kb) {
        int koff = kb * 32 + q * 8;
        bf16x8 bf[4];
        #pragma unroll
        for (int nt = 0; nt < 4; ++nt)
            bf[nt] = *(const bf16x8*)(xt + (nt * 16 + i16) * PX + koff);
        bf16x8 af = *(const bf16x8*)(A1 + (((size_t)w * 8 + kb) * 64 + lane) * 8);
        #pragma unroll
        for (int nt = 0; nt < 4; ++nt) acc[nt] = mfma16(af, bf[nt], acc[nt]);
    }
    #pragma unroll
    for (int nt = 0; nt < 4; ++nt)
        #pragma unroll
        for (int j = 0; j < 4; ++j)
            l0[(nt * 16 + i16) * PL + w * 16 + q * 4 + j] = (bf16_t)acc[nt][j];
    __syncthreads();
    {
        int r = tid >> 4, col = (tid & 15) * 8;
        #pragma unroll
        for (int p = 0; p < 2; ++p) {
            int rr = r + p * 32;
            *(i32x4*)(la + ((size_t)n * 8192 + t0 + rr) * 128 + col) =
                *(const i32x4*)(l0 + rr * PL + col);
        }
    }
    if (t0 >= 4096) {
        f32x4 a2[2][4] = {{z,z,z,z},{z,z,z,z}};
        #pragma unroll
        for (int kb = 0; kb < 4; ++kb) {
            int koff = kb * 32 + q * 8;
            bf16x8 bf[4];
            #pragma unroll
            for (int nt = 0; nt < 4; ++nt)
                bf[nt] = *(const bf16x8*)(l0 + (nt * 16 + i16) * PL + koff);
            #pragma unroll
            for (int mt2 = 0; mt2 < 2; ++mt2) {
                bf16x8 af = *(const bf16x8*)(A2 + ((((size_t)2 * w + mt2) * 4 + kb) * 64 + lane) * 8);
                #pragma unroll
                for (int nt = 0; nt < 4; ++nt) a2[mt2][nt] = mfma16(af, bf[nt], a2[mt2][nt]);
            }
        }
        float* sp = sbuf + (size_t)n * 256 * 4096 + (t0 - 4096);
        #pragma unroll
        for (int mt2 = 0; mt2 < 2; ++mt2)
            #pragma unroll
            for (int nt = 0; nt < 4; ++nt)
                #pragma unroll
                for (int j = 0; j < 4; ++j) {
                    int o = (2 * w + mt2) * 16 + q * 4 + j;
                    sp[(size_t)o * 4096 + nt * 16 + i16] = a2[mt2][nt][j];
                }
    }
}

// ---------------- single layer, TT=32, merged staging for dil<32 ----------------
// USEG=1: stream bf16 gate tile to Gl; skip GEMM deferred to k_skip.
template<int USEG>
__global__ __launch_bounds__(512, 8) void k_layer(
    const bf16_t* __restrict__ l_in, bf16_t* __restrict__ l_out,
    float* __restrict__ sbuf, bf16_t* __restrict__ Gl,
    const bf16_t* __restrict__ Ad, const bf16_t* __restrict__ Ar,
    const bf16_t* __restrict__ Ak, const float* __restrict__ condL,
    int dil, int t_base, int do_res)
{
    __shared__ __align__(16) bf16_t smA[64 * PL];   // staging (cur|del or combined)
    __shared__ __align__(16) bf16_t sm2[32 * PL];   // gate -> res sum
    int tid = threadIdx.x;
    int n = blockIdx.y, t0 = t_base + blockIdx.x * 32;
    int lane = tid & 63, w = tid >> 6, i16 = lane & 15, q = lane >> 4;
    f32x4 z = {0.f,0.f,0.f,0.f};
    const float* cond = condL + (size_t)n * 4096;
    int r = tid >> 4, col = (tid & 15) * 8;
    size_t base = (size_t)n * 8192;
    const bf16_t* curp;
    const bf16_t* delp;
    if (dil < 32) {
        // combined window rows [t0-dil, t0+32): del row r = smA[r], cur row r = smA[r+dil]
        int cnt = (32 + dil) * 16;
        for (int idx = tid; idx < cnt; idx += 512) {
            int rr = idx >> 4, c2 = (idx & 15) * 8;
            *(i32x4*)(smA + rr * PL + c2) =
                *(const i32x4*)(l_in + (base + t0 - dil + rr) * 128 + c2);
        }
        delp = smA; curp = smA + dil * PL;
    } else {
        *(i32x4*)(smA + r * PL + col) =
            *(const i32x4*)(l_in + (base + t0 + r) * 128 + col);
        int gp = t0 - dil + r;
        i32x4 v = {0, 0, 0, 0};
        if (gp >= 0) v = *(const i32x4*)(l_in + (base + gp) * 128 + col);
        *(i32x4*)(smA + (32 + r) * PL + col) = v;
        curp = smA; delp = smA + 32 * PL;
    }
    __syncthreads();

    // GEMM1: d = [W0 W1] @ [l_del; l_cur], M=256 K=256, N=32
    f32x4 accs[2] = {z,z}, acct[2] = {z,z};
    const bf16x8* AdF = (const bf16x8*)Ad;
    #pragma unroll
    for (int kb = 0; kb < 8; ++kb) {
        const bf16_t* bsrc = (kb < 4) ? delp : curp;
        int koff = (kb & 3) * 32 + q * 8;
        bf16x8 bf[2];
        #pragma unroll
        for (int nt = 0; nt < 2; ++nt)
            bf[nt] = *(const bf16x8*)(bsrc + (nt * 16 + i16) * PL + koff);
        bf16x8 a_s = AdF[((size_t)w * 8 + kb) * 64 + lane];
        bf16x8 a_t = AdF[((size_t)(w + 8) * 8 + kb) * 64 + lane];
        #pragma unroll
        for (int nt = 0; nt < 2; ++nt) {
            accs[nt] = mfma16(a_s, bf[nt], accs[nt]);
            acct[nt] = mfma16(a_t, bf[nt], acct[nt]);
        }
    }
    int c_base = w * 16 + q * 4;
    {   // gate in-register -> sm2
        float cv_s[4], cv_t[4];
        #pragma unroll
        for (int j = 0; j < 4; ++j) {
            cv_s[j] = cond[(c_base + j) * 16 + i16];
            cv_t[j] = cond[(c_base + j + 128) * 16 + i16];
        }
        #pragma unroll
        for (int nt = 0; nt < 2; ++nt) {
            bf16x4 g4;
            #pragma unroll
            for (int j = 0; j < 4; ++j) {
                float vlo = accs[nt][j] + cv_s[j];
                float vhi = acct[nt][j] + cv_t[j];
                float sg = 1.0f / (1.0f + __expf(-vlo));
                float th = 1.0f - 2.0f / (1.0f + __expf(2.0f * vhi));
                g4[j] = (bf16_t)(sg * th);
            }
            *(bf16x4*)(sm2 + (nt * 16 + i16) * PL + c_base) = g4;
        }
    }
    __syncthreads();   // gate ready; all GEMM1 LDS reads done

    if (USEG) {
        if (t0 >= 4096) {   // stream gate tile to G
            bf16_t* gd = Gl + ((size_t)n * 4096 + (t0 - 4096) + r) * 128 + col;
            *(i32x4*)gd = *(const i32x4*)(sm2 + r * PL + col);
        }
    }

    f32x4 acc2[2] = {z,z};
    const bf16x8* ArF = (const bf16x8*)Ar;
    if (do_res || !USEG) {
        int do_skip = (!USEG) && (t0 >= 4096);
        f32x4 acc3[2][2] = {{z,z},{z,z}};
        const bf16x8* AkF = (const bf16x8*)Ak;
        #pragma unroll
        for (int kb = 0; kb < 4; ++kb) {
            int koff = kb * 32 + q * 8;
            bf16x8 bf[2];
            #pragma unroll
            for (int nt = 0; nt < 2; ++nt)
                bf[nt] = *(const bf16x8*)(sm2 + (nt * 16 + i16) * PL + koff);
            if (do_res) {
                bf16x8 ar = ArF[((size_t)w * 4 + kb) * 64 + lane];
                #pragma unroll
                for (int nt = 0; nt < 2; ++nt) acc2[nt] = mfma16(ar, bf[nt], acc2[nt]);
            }
            if (do_skip) {
                #pragma unroll
                for (int mt2 = 0; mt2 < 2; ++mt2) {
                    bf16x8 ak = AkF[((size_t)(2 * w + mt2) * 4 + kb) * 64 + lane];
                    #pragma unroll
                    for (int nt = 0; nt < 2; ++nt)
                        acc3[mt2][nt] = mfma16(ak, bf[nt], acc3[mt2][nt]);
                }
            }
        }
        if (do_skip) {
            float* sp = sbuf + (size_t)n * 256 * 4096 + (t0 - 4096);
            #pragma unroll
            for (int mt2 = 0; mt2 < 2; ++mt2)
                #pragma unroll
                for (int nt = 0; nt < 2; ++nt)
                    #pragma unroll
                    for (int j = 0; j < 4; ++j) {
                        int o = (2 * w + mt2) * 16 + q * 4 + j;
                        sp[(size_t)o * 4096 + nt * 16 + i16] += acc3[mt2][nt][j];
                    }
        }
    }

    if (do_res) {
        // sum = f32(l_cur) + res in regs; barrier; stage via sm2; coalesced store
        bf16x4 o4[2];
        #pragma unroll
        for (int nt = 0; nt < 2; ++nt) {
            int trow = (nt * 16 + i16) * PL;
            bf16x4 lv = *(const bf16x4*)(curp + trow + c_base);
            #pragma unroll
            for (int j = 0; j < 4; ++j)
                o4[nt][j] = (bf16_t)((float)lv[j] + acc2[nt][j]);
        }
        __syncthreads();   // all gate reads + lv reads done
        #pragma unroll
        for (int nt = 0; nt < 2; ++nt)
            *(bf16x4*)(sm2 + (nt * 16 + i16) * PL + c_base) = o4[nt];
        __syncthreads();
        bf16_t* dst = l_out + (base + t0 + r) * 128 + col;
        *(i32x4*)dst = *(const i32x4*)(sm2 + r * PL + col);
    }
}

// ---------------- deferred skip mega-GEMM: s += sum_i skip_i @ g_i ----------------
// TT=32, double-buffered LDS (1 barrier/phase) + depth-4 register prefetch ring.
__global__ __launch_bounds__(512, 8) void k_skip(
    const bf16_t* __restrict__ G, float* __restrict__ sbuf,
    const bf16_t* __restrict__ Askp)
{
    __shared__ __align__(16) bf16_t gbuf[2][32 * PL];
    int tid = threadIdx.x;
    int n = blockIdx.y, t0 = blockIdx.x * 32;
    int lane = tid & 63, w = tid >> 6, i16 = lane & 15, q = lane >> 4;
    f32x4 z = {0.f,0.f,0.f,0.f};
    f32x4 acc[2][2] = {{z,z},{z,z}};
    int r = tid >> 4, cA = (tid & 15) * 8;
    const size_t GLS = (size_t)4 * 4096 * 128;   // per-layer stride in G
    const bf16_t* gb = G + ((size_t)n * 4096 + t0 + r) * 128 + cA;
    i32x4 v[4];
    #pragma unroll
    for (int d = 0; d < 4; ++d) v[d] = *(const i32x4*)(gb + (size_t)d * GLS);
    #pragma unroll 1
    for (int i = 0; i < 30; ++i) {
        // store layer i into buf[i&1]; safe: all waves finished compute i-2 (barrier i-1)
        *(i32x4*)(gbuf[i & 1] + r * PL + cA) = v[i & 3];
        if (i + 4 < 30) v[i & 3] = *(const i32x4*)(gb + (size_t)(i + 4) * GLS);
        __syncthreads();
        const bf16x8* AkF = (const bf16x8*)(Askp + (size_t)i * 32768);
        const bf16_t* gB = gbuf[i & 1];
        #pragma unroll
        for (int kb = 0; kb < 4; ++kb) {
            int koff = kb * 32 + q * 8;
            bf16x8 ak0 = AkF[((size_t)(2 * w) * 4 + kb) * 64 + lane];
            bf16x8 ak1 = AkF[((size_t)(2 * w + 1) * 4 + kb) * 64 + lane];
            #pragma unroll
            for (int nt = 0; nt < 2; ++nt) {
                bf16x8 bf = *(const bf16x8*)(gB + (nt * 16 + i16) * PL + koff);
                acc[0][nt] = mfma16(ak0, bf, acc[0][nt]);
                acc[1][nt] = mfma16(ak1, bf, acc[1][nt]);
            }
        }
    }
    float* sp = sbuf + (size_t)n * 256 * 4096 + t0;
    #pragma unroll
    for (int mt2 = 0; mt2 < 2; ++mt2)
        #pragma unroll
        for (int nt = 0; nt < 2; ++nt)
            #pragma unroll
            for (int j = 0; j < 4; ++j) {
                int o = (2 * w + mt2) * 16 + q * 4 + j;
                sp[(size_t)o * 4096 + nt * 16 + i16] += acc[mt2][nt][j];
            }
}

// ---------------- end: out = relu(end1@relu(s) + b1 + cond2_tiled) ----------------
__global__ __launch_bounds__(512) void k_end(
    const float* __restrict__ sbuf, float* __restrict__ out,
    const bf16_t* __restrict__ Ae, const float* __restrict__ cond2,
    const float* __restrict__ b1)
{
    __shared__ __align__(16) bf16_t st[64 * PX];
    __shared__ float c2[4096];
    __shared__ float b1s[256];
    int tid = threadIdx.x;
    int n = blockIdx.y, t0 = blockIdx.x * 64;
    int lane = tid & 63, w = tid >> 6, i16 = lane & 15, q = lane >> 4;
    f32x4 z = {0.f,0.f,0.f,0.f};
    {
        int t = tid & 63;
        for (int c = tid >> 6; c < 256; c += 8) {
            float v = sbuf[((size_t)n * 256 + c) * 4096 + t0 + t];
            st[t * PX + c] = (bf16_t)fmaxf(v, 0.f);
        }
        const f32x4* cc = (const f32x4*)(cond2 + (size_t)n * 4096);
        for (int idx = tid; idx < 1024; idx += 512) ((f32x4*)c2)[idx] = cc[idx];
        if (tid < 64) ((f32x4*)b1s)[tid] = ((const f32x4*)b1)[tid];
    }
    __syncthreads();
    f32x4 acc[2][4] = {{z,z,z,z},{z,z,z,z}};
    #pragma unroll
    for (int kb = 0; kb < 8; ++kb) {
        int koff = kb * 32 + q * 8;
        bf16x8 bf[4];
        #pragma unroll
        for (int nt = 0; nt < 4; ++nt)
            bf[nt] = *(const bf16x8*)(st + (nt * 16 + i16) * PX + koff);
        #pragma unroll
        for (int mt2 = 0; mt2 < 2; ++mt2) {
            bf16x8 af = *(const bf16x8*)(Ae + ((((size_t)2 * w + mt2) * 8 + kb) * 64 + lane) * 8);
            #pragma unroll
            for (int nt = 0; nt < 4; ++nt) acc[mt2][nt] = mfma16(af, bf[nt], acc[mt2][nt]);
        }
    }
    #pragma unroll
    for (int mt2 = 0; mt2 < 2; ++mt2)
        #pragma unroll
        for (int j = 0; j < 4; ++j) {
            int o = (2 * w + mt2) * 16 + q * 4 + j;
            float bb = b1s[o] + c2[o * 16 + i16];
            #pragma unroll
            for (int nt = 0; nt < 4; ++nt) {
                float v = acc[mt2][nt][j] + bb;
                out[((size_t)n * 256 + o) * 4096 + t0 + nt * 16 + i16] = fmaxf(v, 0.f);
            }
        }
}

extern "C" void kernel_launch(void* const* d_in, const int* in_sizes, int n_in,
                              void* d_out, int out_size, void* d_ws, size_t ws_size,
                              hipStream_t stream) {
    const float* x   = (const float*)d_in[0];
    const float* en  = (const float*)d_in[1];
    const float* s1w = (const float*)d_in[2];
    const float* s2w = (const float*)d_in[3];
    const float* cw  = (const float*)d_in[4];
    const float* dw  = (const float*)d_in[5];
    const float* rw  = (const float*)d_in[6];
    const float* kw  = (const float*)d_in[7];
    const float* e1w = (const float*)d_in[8];
    const float* e1b = (const float*)d_in[9];
    const float* e2w = (const float*)d_in[10];
    const float* e2b = (const float*)d_in[11];
    float* out = (float*)d_out;

    char* p = (char*)d_ws;
    auto take = [&](size_t bytes) {
        char* r = p;
        p += (bytes + 255) & ~(size_t)255;
        return r;
    };
    bf16_t* A1   = (bf16_t*)take((size_t)128 * 256 * 2);
    bf16_t* A2   = (bf16_t*)take((size_t)256 * 128 * 2);
    bf16_t* Ae   = (bf16_t*)take((size_t)256 * 256 * 2);
    bf16_t* Adil = (bf16_t*)take((size_t)30 * 65536 * 2);
    bf16_t* Ares = (bf16_t*)take((size_t)30 * 16384 * 2);
    bf16_t* Askp = (bf16_t*)take((size_t)30 * 32768 * 2);
    float*  condA= (float*)take((size_t)30 * 16384 * 4);
    float*  cond2= (float*)take((size_t)16384 * 4);
    bf16_t* la   = (bf16_t*)take((size_t)4 * 8192 * 128 * 2);
    bf16_t* lb   = (bf16_t*)take((size_t)4 * 8192 * 128 * 2);
    float*  sbuf = (float*)take((size_t)4 * 256 * 4096 * 4);
    bf16_t* G    = (bf16_t*)take((size_t)30 * 4 * 4096 * 128 * 2);  // last
    bool useG = ((size_t)(p - (char*)d_ws) <= ws_size);

    k_prep<<<14076, 256, 0, stream>>>(rw, kw, s1w, s2w, e1w, dw,
                                      cw, e2w, e2b, en,
                                      Ares, Askp, A1, A2, Ae, Adil, condA, cond2);

    // causal trim table (host)
    int a[30];
    a[29] = 4096;
    for (int i = 28; i >= 0; --i) {
        int nx = a[i + 1] - (1 << ((i + 1) % 10));
        a[i] = nx < 4096 ? (nx & ~63) : 4096;
    }

    k_start<<<dim3(127, 4), 512, 0, stream>>>(x, la, sbuf, A1, A2, 64);

    bf16_t* src = la;
    bf16_t* dst = lb;
    for (int i = 0; i < 30; ++i) {
        dim3 grid((8192 - a[i]) / 32, 4);
        if (useG)
            k_layer<1><<<grid, 512, 0, stream>>>(src, dst, sbuf,
                G + (size_t)i * 4 * 4096 * 128,
                Adil + (size_t)i * 65536, Ares + (size_t)i * 16384,
                Askp + (size_t)i * 32768, condA + (size_t)i * 16384,
                1 << (i % 10), a[i], i < 29 ? 1 : 0);
        else
            k_layer<0><<<grid, 512, 0, stream>>>(src, dst, sbuf, (bf16_t*)nullptr,
                Adil + (size_t)i * 65536, Ares + (size_t)i * 16384,
                Askp + (size_t)i * 32768, condA + (size_t)i * 16384,
                1 << (i % 10), a[i], i < 29 ? 1 : 0);
        bf16_t* t = src; src = dst; dst = t;
    }
    if (useG)
        k_skip<<<dim3(128, 4), 512, 0, stream>>>(G, sbuf, Askp);
    k_end<<<dim3(64, 4), 512, 0, stream>>>(sbuf, out, Ae, cond2, e1b);
}